// Round 2
// baseline (158.525 us; speedup 1.0000x reference)
//
#include <hip/hip_runtime.h>
#include <hip/hip_cooperative_groups.h>

namespace cg = cooperative_groups;

// GroundPlane: RANSAC plane fit + signed distance map.
// B=4, points (B,3,H=384,W=1280) f32; rand_ind (B,125) i32.
// gH=192, N=gH*W=245760 (bottom-half cloud = tail rows of each channel, contiguous).
// Reference quirk: ps = tile(gp,(25,1,1)) => plane m=b*25+it is scored against
// point-batch (b+it)%4 (25 = 1 mod 4). Replicated here.
//
// R2: scratch spill fix 210->93us. R4: fit folded into k_count -> 87us.
// R5: no memset node / no global atomics (race-free partials). R6: all 25
// planes per point-batch in ONE pass, f32 eval -> 85.6us (small: cloud was
// L3-resident so the 5x re-read was cheap -- lesson learned).
// R7 (this): fuse count+dist into ONE cooperative kernel (480 blocks):
//  - bottom-half data held in REGISTERS across grid.sync (no re-read),
//  - top-half float4s PREFETCHED before the counting loop (cold HBM traffic
//    overlaps the ~2us of 25-plane VALU work),
//  - kernel boundary (drain + node gap) replaced by grid.sync.
// Fallback to the 2-kernel path if cooperative launch is rejected.

constexpr int BN      = 4;
constexpr int H       = 384;
constexpr int W       = 1280;
constexpr int HW      = H * W;          // 491520
constexpr int GH      = 192;            // int(0.5*H)
constexpr int NPTS    = GH * W;         // 245760
constexpr int MAX_IT  = 25;
constexpr int NUM_PTS = 5;
constexpr int TOTAL_P = BN * MAX_IT;    // 100 planes

constexpr int PLANES_PB    = 25;                   // planes scored per point-batch
constexpr int CH_F4        = 512;                  // float4 per chunk
constexpr int CHUNKS       = (NPTS / 4) / CH_F4;   // 120
constexpr int ITERS        = CH_F4 / 256;          // 2 float4 per thread
constexpr int PSTRIDE      = 128;                  // partial row stride (int4-aligned)
constexpr int GRID         = BN * CHUNKS;          // 480 blocks (co-resident: 2/CU)
constexpr int TOPF4_PB     = (HW / 2) / 4;         // 61440 top-half float4 per batch
constexpr int THREADS_TOT  = GRID * 256;           // 122880 (= TOPF4_PB*4/2)
constexpr int BLOCKS_PER_B = (HW / 4) / 256;       // 480 (fallback k_dist)

// ---------------- shared fit routine (threads 0..24 of a block) -------------
__device__ __forceinline__ void fit_planes(
        const float* __restrict__ pts, const int* __restrict__ rind,
        float* __restrict__ wsf, int pb, bool publish, int tid,
        float (*sw)[3], int* spid) {
    // enumerate planes (b,it) with (b+it)%4==pb; pick the tid-th
    int s = 0, pi = 0;
    for (int b = 0; b < BN; ++b) {
        int r = ((pb - b) % BN + BN) % BN;
        for (int it = r; it < MAX_IT; it += BN) {
            if (s == tid) pi = b * MAX_IT + it;
            ++s;
        }
    }
    spid[tid] = pi;
    // --- fit plane pi from batch (pi/25)'s sampled points, f64 Cramer ---
    int fb = pi / MAX_IT, fit_it = pi % MAX_IT;
    const float* base = pts + (size_t)fb * 3 * HW + (size_t)(H - GH) * W;
    const int* ri = rind + fb * (MAX_IT * NUM_PTS) + fit_it * NUM_PTS;
    double Sxx = 0, Sxz = 0, Sx = 0, Szz = 0, Sz = 0, Sxy = 0, Szy = 0, Sy = 0;
#pragma unroll
    for (int p = 0; p < NUM_PTS; ++p) {
        int n = ri[p];
        double x = (double)base[n];
        double y = (double)base[HW + n];        // VAX=1 -> y is the "B" column
        double z = (double)base[2 * HW + n];
        Sxx += x * x; Sxz += x * z; Sx += x;
        Szz += z * z; Sz += z;
        Sxy += x * y; Szy += z * y; Sy += y;
    }
    const double e = 1e-6;   // AtA + 1e-6 broadcasts onto ALL nine entries
    double m00 = Sxx + e, m01 = Sxz + e, m02 = Sx + e;
    double m10 = Sxz + e, m11 = Szz + e, m12 = Sz + e;
    double m20 = Sx + e,  m21 = Sz + e,  m22 = (double)NUM_PTS + e;
    double v0 = Sxy, v1 = Szy, v2 = Sy;
    double det = m00 * (m11 * m22 - m12 * m21)
               - m01 * (m10 * m22 - m12 * m20)
               + m02 * (m10 * m21 - m11 * m20);
    double inv = 1.0 / det;
    double d0 = v0  * (m11 * m22 - m12 * m21)
              - m01 * (v1  * m22 - m12 * v2 )
              + m02 * (v1  * m21 - m11 * v2 );
    double d1 = m00 * (v1  * m22 - m12 * v2 )
              - v0  * (m10 * m22 - m12 * m20)
              + m02 * (m10 * v2  - v1  * m20);
    double d2 = m00 * (m11 * v2  - v1  * m21)
              - m01 * (m10 * v2  - v1  * m20)
              + v0  * (m10 * m21 - m11 * m20);
    double w0 = d0 * inv, w1 = d1 * inv, w2 = d2 * inv;
    sw[tid][0] = (float)w0; sw[tid][1] = (float)w1; sw[tid][2] = (float)w2;
    if (publish) {   // chunk==0 blocks: 4 blocks cover all 100 planes
        wsf[pi * 3 + 0] = (float)w0;
        wsf[pi * 3 + 1] = (float)w1;
        wsf[pi * 3 + 2] = (float)w2;
    }
}

// ---------------- fused cooperative kernel ----------------------------------
__global__ __launch_bounds__(256, 2) void k_fused(
        const float* __restrict__ pts, const int* __restrict__ rind,
        float* __restrict__ wsf, int* __restrict__ partial,
        float* __restrict__ out) {
    __shared__ float sw[PLANES_PB][3];
    __shared__ int   spid[PLANES_PB];
    __shared__ int   sacc[PLANES_PB];
    __shared__ int   scnt[TOTAL_P];
    __shared__ float swv[BN][3];

    int pb    = blockIdx.x & 3;          // point-batch
    int chunk = blockIdx.x >> 2;         // [0, CHUNKS)
    int tid   = threadIdx.x;
    if (tid < PLANES_PB) {
        sacc[tid] = 0;
        fit_planes(pts, rind, wsf, pb, chunk == 0, tid, sw, spid);
    }
    __syncthreads();
    // hoist all 25 plane weights to registers (75 f32)
    float w0[PLANES_PB], w1[PLANES_PB], w2[PLANES_PB];
#pragma unroll
    for (int p = 0; p < PLANES_PB; ++p) {
        w0[p] = sw[p][0]; w1[p] = sw[p][1]; w2[p] = sw[p][2];
    }

    // ---- bottom-half loads (held in registers across grid.sync) ----
    const float* base = pts + (size_t)pb * 3 * HW + (size_t)(H - GH) * W;
    const float4* px = (const float4*)base;
    const float4* py = (const float4*)(base + HW);
    const float4* pz = (const float4*)(base + 2 * HW);
    float4 bx[ITERS], by[ITERS], bz[ITERS];
#pragma unroll
    for (int it = 0; it < ITERS; ++it) {
        int f = chunk * CH_F4 + it * 256 + tid;
        bx[it] = px[f]; by[it] = py[f]; bz[it] = pz[f];
    }
    // ---- top-half prefetch (cold HBM; overlaps the counting VALU work) ----
    int T = blockIdx.x * 256 + tid;
    float4 tx[2], ty[2], tz[2];
    int tb[2], tf[2];
#pragma unroll
    for (int j = 0; j < 2; ++j) {
        int idx = j * THREADS_TOT + T;      // [0, 4*TOPF4_PB)
        int bt  = idx / TOPF4_PB;
        int ft  = idx - bt * TOPF4_PB;
        tb[j] = bt; tf[j] = ft;
        const float4* qx = (const float4*)(pts + (size_t)bt * 3 * HW);
        tx[j] = qx[ft];
        ty[j] = qx[HW / 4 + ft];
        tz[j] = qx[2 * (HW / 4) + ft];
    }

    // ---- count inliers for all 25 planes ----
    int cnt[PLANES_PB];
#pragma unroll
    for (int p = 0; p < PLANES_PB; ++p) cnt[p] = 0;
#pragma unroll
    for (int it = 0; it < ITERS; ++it) {
        float4 x4 = bx[it], y4 = by[it], z4 = bz[it];
#pragma unroll
        for (int e = 0; e < 4; ++e) {
            float x = ((const float*)&x4)[e];
            float y = ((const float*)&y4)[e];
            float z = ((const float*)&z4)[e];
#pragma unroll
            for (int p = 0; p < PLANES_PB; ++p) {
                float d = fmaf(x, w0[p], fmaf(z, w1[p], w2[p] - y));
                cnt[p] += (fabsf(d) < 0.1f) ? 1 : 0;
            }
        }
    }
    // wave reduce -> LDS block reduce -> ONE plain store per plane per block
#pragma unroll
    for (int p = 0; p < PLANES_PB; ++p) {
        int v = cnt[p];
        for (int off = 32; off > 0; off >>= 1) v += __shfl_down(v, off, 64);
        if ((tid & 63) == 0) atomicAdd(&sacc[p], v);
    }
    __syncthreads();
    if (tid < PLANES_PB) partial[spid[tid] * PSTRIDE + chunk] = sacc[tid];
    __threadfence();

    cg::this_grid().sync();

    // ---- per-block redundant partial-sum + argmax (L2-hot) ----
    if (tid < TOTAL_P) {   // thread t sums plane t's 120 chunk-partials (int4)
        const int4* p = (const int4*)(partial + tid * PSTRIDE);
        int s = 0;
#pragma unroll
        for (int c = 0; c < CHUNKS / 4; ++c) {
            int4 v = p[c];
            s += v.x + v.y + v.z + v.w;
        }
        scnt[tid] = s;
    }
    __syncthreads();
    if (tid < BN) {
        int b = tid;
        int best = 0, bc = scnt[b * MAX_IT];
        for (int it = 1; it < MAX_IT; ++it) {
            int c = scnt[b * MAX_IT + it];
            if (c > bc) { bc = c; best = it; }   // strict > : first-max == np argmax
        }
        int pi = b * MAX_IT + best;
        float v0 = wsf[pi * 3 + 0], v1 = wsf[pi * 3 + 1], v2 = wsf[pi * 3 + 2];
        swv[b][0] = v0; swv[b][1] = v1; swv[b][2] = v2;
        if (blockIdx.x == 0) {   // best_w tail: (B,3,1) = 12 floats
            out[(size_t)BN * HW + b * 3 + 0] = v0;
            out[(size_t)BN * HW + b * 3 + 1] = v1;
            out[(size_t)BN * HW + b * 3 + 2] = v2;
        }
    }
    __syncthreads();

    // ---- bottom-half dist from HELD registers (no re-read) ----
    {
        float u0 = swv[pb][0], u1 = swv[pb][1], u2 = swv[pb][2];
        float4* ob = (float4*)(out + (size_t)pb * HW + HW / 2);
#pragma unroll
        for (int it = 0; it < ITERS; ++it) {
            int f = chunk * CH_F4 + it * 256 + tid;
            float4 x4 = bx[it], y4 = by[it], z4 = bz[it];
            float4 r;
            r.x = fmaf(x4.x, u0, fmaf(z4.x, u1, u2 - y4.x));
            r.y = fmaf(x4.y, u0, fmaf(z4.y, u1, u2 - y4.y));
            r.z = fmaf(x4.z, u0, fmaf(z4.z, u1, u2 - y4.z));
            r.w = fmaf(x4.w, u0, fmaf(z4.w, u1, u2 - y4.w));
            ob[f] = r;
        }
    }
    // ---- top-half dist from PREFETCHED registers ----
#pragma unroll
    for (int j = 0; j < 2; ++j) {
        float u0 = swv[tb[j]][0], u1 = swv[tb[j]][1], u2 = swv[tb[j]][2];
        float4 x4 = tx[j], y4 = ty[j], z4 = tz[j];
        float4 r;
        r.x = fmaf(x4.x, u0, fmaf(z4.x, u1, u2 - y4.x));
        r.y = fmaf(x4.y, u0, fmaf(z4.y, u1, u2 - y4.y));
        r.z = fmaf(x4.z, u0, fmaf(z4.z, u1, u2 - y4.z));
        r.w = fmaf(x4.w, u0, fmaf(z4.w, u1, u2 - y4.w));
        ((float4*)(out + (size_t)tb[j] * HW))[tf[j]] = r;
    }
}

// ---------------- fallback path (R6 two-kernel version) ---------------------
__global__ __launch_bounds__(256) void k_count(
        const float* __restrict__ pts, const int* __restrict__ rind,
        float* __restrict__ wsf, int* __restrict__ partial) {
    __shared__ float sw[PLANES_PB][3];
    __shared__ int   spid[PLANES_PB];
    __shared__ int   sacc[PLANES_PB];
    int pb    = blockIdx.x & 3;
    int chunk = blockIdx.x >> 2;
    int tid   = threadIdx.x;
    if (tid < PLANES_PB) {
        sacc[tid] = 0;
        fit_planes(pts, rind, wsf, pb, chunk == 0, tid, sw, spid);
    }
    __syncthreads();
    float w0[PLANES_PB], w1[PLANES_PB], w2[PLANES_PB];
#pragma unroll
    for (int p = 0; p < PLANES_PB; ++p) {
        w0[p] = sw[p][0]; w1[p] = sw[p][1]; w2[p] = sw[p][2];
    }
    const float* base = pts + (size_t)pb * 3 * HW + (size_t)(H - GH) * W;
    const float4* px = (const float4*)base;
    const float4* py = (const float4*)(base + HW);
    const float4* pz = (const float4*)(base + 2 * HW);
    int cnt[PLANES_PB];
#pragma unroll
    for (int p = 0; p < PLANES_PB; ++p) cnt[p] = 0;
#pragma unroll
    for (int it = 0; it < ITERS; ++it) {
        int f = chunk * CH_F4 + it * 256 + tid;
        float4 x4 = px[f], y4 = py[f], z4 = pz[f];
#pragma unroll
        for (int e = 0; e < 4; ++e) {
            float x = ((const float*)&x4)[e];
            float y = ((const float*)&y4)[e];
            float z = ((const float*)&z4)[e];
#pragma unroll
            for (int p = 0; p < PLANES_PB; ++p) {
                float d = fmaf(x, w0[p], fmaf(z, w1[p], w2[p] - y));
                cnt[p] += (fabsf(d) < 0.1f) ? 1 : 0;
            }
        }
    }
#pragma unroll
    for (int p = 0; p < PLANES_PB; ++p) {
        int v = cnt[p];
        for (int off = 32; off > 0; off >>= 1) v += __shfl_down(v, off, 64);
        if ((tid & 63) == 0) atomicAdd(&sacc[p], v);
    }
    __syncthreads();
    if (tid < PLANES_PB) partial[spid[tid] * PSTRIDE + chunk] = sacc[tid];
}

__global__ __launch_bounds__(256) void k_dist(
        const float* __restrict__ pts, const float* __restrict__ wsf,
        const int* __restrict__ partial, float* __restrict__ out) {
    __shared__ int   scnt[MAX_IT];
    __shared__ float sw[3];
    int b   = blockIdx.x / BLOCKS_PER_B;
    int blk = blockIdx.x % BLOCKS_PER_B;
    int tid = threadIdx.x;
    if (tid < MAX_IT) {
        const int4* p = (const int4*)(partial + (b * MAX_IT + tid) * PSTRIDE);
        int s = 0;
#pragma unroll
        for (int c = 0; c < CHUNKS / 4; ++c) {
            int4 v = p[c];
            s += v.x + v.y + v.z + v.w;
        }
        scnt[tid] = s;
    }
    __syncthreads();
    if (tid == 0) {
        int best = 0, bc = scnt[0];
        for (int it = 1; it < MAX_IT; ++it) {
            int c = scnt[it];
            if (c > bc) { bc = c; best = it; }
        }
        int pi = b * MAX_IT + best;
        sw[0] = wsf[pi * 3 + 0];
        sw[1] = wsf[pi * 3 + 1];
        sw[2] = wsf[pi * 3 + 2];
        if (blk == 0) {
            out[(size_t)BN * HW + b * 3 + 0] = sw[0];
            out[(size_t)BN * HW + b * 3 + 1] = sw[1];
            out[(size_t)BN * HW + b * 3 + 2] = sw[2];
        }
    }
    __syncthreads();
    float w0 = sw[0], w1 = sw[1], w2 = sw[2];
    const float4* px = (const float4*)(pts + (size_t)b * 3 * HW);
    const float4* py = px + HW / 4;
    const float4* pz = py + HW / 4;
    int i = blk * 256 + tid;
    float4 x = px[i], y = py[i], z = pz[i];
    float4 r;
    r.x = w0 * x.x + w1 * z.x + w2 - y.x;
    r.y = w0 * x.y + w1 * z.y + w2 - y.y;
    r.z = w0 * x.z + w1 * z.z + w2 - y.z;
    r.w = w0 * x.w + w1 * z.w + w2 - y.w;
    ((float4*)(out + (size_t)b * HW))[i] = r;
}

extern "C" void kernel_launch(void* const* d_in, const int* in_sizes, int n_in,
                              void* d_out, int out_size, void* d_ws, size_t ws_size,
                              hipStream_t stream) {
    const float* pts  = (const float*)d_in[0];
    const int*   rind = (const int*)d_in[1];
    float* out = (float*)d_out;

    float* wsf     = (float*)d_ws;                  // 300 floats
    int*   partial = (int*)(wsf + TOTAL_P * 3 + 4); // 100*128 ints (each slot
                                                    // written before read; no init)

    void* args[5] = {(void*)&pts, (void*)&rind, (void*)&wsf, (void*)&partial,
                     (void*)&out};
    hipError_t err = hipLaunchCooperativeKernel((const void*)k_fused,
                                                dim3(GRID), dim3(256),
                                                args, 0, stream);
    if (err != hipSuccess) {
        (void)hipGetLastError();   // clear; fall back to 2-kernel path
        k_count<<<GRID, 256, 0, stream>>>(pts, rind, wsf, partial);
        k_dist <<<BN * BLOCKS_PER_B, 256, 0, stream>>>(pts, wsf, partial, out);
    }
}

// Round 3
// 83.848 us; speedup vs baseline: 1.8906x; 1.8906x over previous
//
#include <hip/hip_runtime.h>

// GroundPlane: RANSAC plane fit + signed distance map.
// B=4, points (B,3,H=384,W=1280) f32; rand_ind (B,125) i32.
// gH=192, N=gH*W=245760 (bottom-half cloud = tail rows of each channel, contiguous).
// Reference quirk: ps = tile(gp,(25,1,1)) => plane m=b*25+it is scored against
// point-batch (b+it)%4 (25 = 1 mod 4). Replicated here.
//
// R2: scratch spill fix 210->93us. R4: fit folded into k_count -> 87us.
// R5: no memset node / no global atomics (race-free partials) -> 86.6us.
// R6: all 25 planes per point-batch in ONE pass, f32 eval -> 85.6us
//     (gain small: cloud is L3-resident, the 5x re-read was cheap).
// R7 FAILED (158us): cooperative-kernel fusion. ockl grid-sync spins with
//     s_sleep backoff across 8 XCDs -> k_fused alone 76us @ 5% VALUBusy.
//     Grid-wide sync is NOT a cheap primitive here; custom barrier unsafe
//     (arrive counter lives in poisoned ws, no init node). REVERTED.
// R8 (this): R6 structure + parallelized k_dist partial-sum (250 threads,
//     3-deep load chain instead of 25 threads x 30-deep). Remaining time is
//     harness-fixed: 44us ws poison fill + restore nodes + ~9us of our work.

constexpr int BN      = 4;
constexpr int H       = 384;
constexpr int W       = 1280;
constexpr int HW      = H * W;          // 491520
constexpr int GH      = 192;            // int(0.5*H)
constexpr int NPTS    = GH * W;         // 245760
constexpr int MAX_IT  = 25;
constexpr int NUM_PTS = 5;
constexpr int TOTAL_P = BN * MAX_IT;    // 100 planes

constexpr int PLANES_PB    = 25;                   // planes scored per point-batch
constexpr int CH_F4        = 512;                  // float4 per chunk
constexpr int CHUNKS       = (NPTS / 4) / CH_F4;   // 120
constexpr int ITERS        = CH_F4 / 256;          // 2 float4 per thread
constexpr int PSTRIDE      = 128;                  // partial row stride (int4-aligned)
constexpr int SEGS         = 10;                   // k_dist partial-sum segments/plane
constexpr int SEG_I4       = CHUNKS / SEGS / 4;    // 3 int4 per segment
constexpr int BLOCKS_PER_B = (HW / 4) / 256;       // 480 (k_dist)

// ---- Kernel 1: fit (redundant per block, threads 0..24) + partial counts ----
__global__ __launch_bounds__(256) void k_count(
        const float* __restrict__ pts, const int* __restrict__ rind,
        float* __restrict__ wsf, int* __restrict__ partial) {
    __shared__ float sw[PLANES_PB][3];
    __shared__ int   spid[PLANES_PB];
    __shared__ int   sacc[PLANES_PB];
    int pb    = blockIdx.x & 3;          // point-batch
    int chunk = blockIdx.x >> 2;         // [0, CHUNKS)
    int tid   = threadIdx.x;
    if (tid < PLANES_PB) {
        sacc[tid] = 0;
        // enumerate planes (b,it) with (b+it)%4==pb; pick the tid-th
        int s = 0, pi = 0;
        for (int b = 0; b < BN; ++b) {
            int r = ((pb - b) % BN + BN) % BN;
            for (int it = r; it < MAX_IT; it += BN) {
                if (s == tid) pi = b * MAX_IT + it;
                ++s;
            }
        }
        spid[tid] = pi;
        // --- fit plane pi from batch (pi/25)'s sampled points, f64 Cramer ---
        int fb = pi / MAX_IT, fit_it = pi % MAX_IT;
        const float* base = pts + (size_t)fb * 3 * HW + (size_t)(H - GH) * W;
        const int* ri = rind + fb * (MAX_IT * NUM_PTS) + fit_it * NUM_PTS;
        double Sxx = 0, Sxz = 0, Sx = 0, Szz = 0, Sz = 0, Sxy = 0, Szy = 0, Sy = 0;
#pragma unroll
        for (int p = 0; p < NUM_PTS; ++p) {
            int n = ri[p];
            double x = (double)base[n];
            double y = (double)base[HW + n];        // VAX=1 -> y is the "B" column
            double z = (double)base[2 * HW + n];
            Sxx += x * x; Sxz += x * z; Sx += x;
            Szz += z * z; Sz += z;
            Sxy += x * y; Szy += z * y; Sy += y;
        }
        const double e = 1e-6;   // AtA + 1e-6 broadcasts onto ALL nine entries
        double m00 = Sxx + e, m01 = Sxz + e, m02 = Sx + e;
        double m10 = Sxz + e, m11 = Szz + e, m12 = Sz + e;
        double m20 = Sx + e,  m21 = Sz + e,  m22 = (double)NUM_PTS + e;
        double v0 = Sxy, v1 = Szy, v2 = Sy;
        double det = m00 * (m11 * m22 - m12 * m21)
                   - m01 * (m10 * m22 - m12 * m20)
                   + m02 * (m10 * m21 - m11 * m20);
        double inv = 1.0 / det;
        double d0 = v0  * (m11 * m22 - m12 * m21)
                  - m01 * (v1  * m22 - m12 * v2 )
                  + m02 * (v1  * m21 - m11 * v2 );
        double d1 = m00 * (v1  * m22 - m12 * v2 )
                  - v0  * (m10 * m22 - m12 * m20)
                  + m02 * (m10 * v2  - v1  * m20);
        double d2 = m00 * (m11 * v2  - v1  * m21)
                  - m01 * (m10 * v2  - v1  * m20)
                  + v0  * (m10 * m21 - m11 * m20);
        double w0 = d0 * inv, w1 = d1 * inv, w2 = d2 * inv;
        sw[tid][0] = (float)w0; sw[tid][1] = (float)w1; sw[tid][2] = (float)w2;
        if (chunk == 0) {   // publish f32 weights for k_dist (4 blocks cover all 100)
            wsf[pi * 3 + 0] = (float)w0;
            wsf[pi * 3 + 1] = (float)w1;
            wsf[pi * 3 + 2] = (float)w2;
        }
    }
    __syncthreads();
    // hoist all 25 plane weights to registers (75 f32)
    float w0[PLANES_PB], w1[PLANES_PB], w2[PLANES_PB];
#pragma unroll
    for (int p = 0; p < PLANES_PB; ++p) {
        w0[p] = sw[p][0]; w1[p] = sw[p][1]; w2[p] = sw[p][2];
    }

    const float* base = pts + (size_t)pb * 3 * HW + (size_t)(H - GH) * W;
    const float4* px = (const float4*)base;
    const float4* py = (const float4*)(base + HW);
    const float4* pz = (const float4*)(base + 2 * HW);

    int cnt[PLANES_PB];
#pragma unroll
    for (int p = 0; p < PLANES_PB; ++p) cnt[p] = 0;

#pragma unroll
    for (int it = 0; it < ITERS; ++it) {
        int f = chunk * CH_F4 + it * 256 + tid;
        float4 x4 = px[f], y4 = py[f], z4 = pz[f];
#pragma unroll
        for (int e = 0; e < 4; ++e) {
            float x = ((const float*)&x4)[e];
            float y = ((const float*)&y4)[e];
            float z = ((const float*)&z4)[e];
#pragma unroll
            for (int p = 0; p < PLANES_PB; ++p) {
                float d = fmaf(x, w0[p], fmaf(z, w1[p], w2[p] - y));
                cnt[p] += (fabsf(d) < 0.1f) ? 1 : 0;
            }
        }
    }
    // wave reduce -> LDS block reduce -> ONE plain store per plane per block
    // (partial[pi][chunk] is written by exactly one block: race-free, no init)
#pragma unroll
    for (int p = 0; p < PLANES_PB; ++p) {
        int v = cnt[p];
        for (int off = 32; off > 0; off >>= 1) v += __shfl_down(v, off, 64);
        if ((tid & 63) == 0) atomicAdd(&sacc[p], v);
    }
    __syncthreads();
    if (tid < PLANES_PB) partial[spid[tid] * PSTRIDE + chunk] = sacc[tid];
}

// -- Kernel 2: per-batch partial-sum + argmax (redundant, L2-hot) + dist map --
__global__ __launch_bounds__(256) void k_dist(
        const float* __restrict__ pts, const float* __restrict__ wsf,
        const int* __restrict__ partial, float* __restrict__ out) {
    __shared__ int   scnt[MAX_IT];
    __shared__ float sw[3];
    int b   = blockIdx.x / BLOCKS_PER_B;
    int blk = blockIdx.x % BLOCKS_PER_B;
    int tid = threadIdx.x;
    if (tid < MAX_IT) scnt[tid] = 0;
    __syncthreads();
    // parallel partial-sum: 250 threads, plane = tid/10, segment = tid%10,
    // 3 int4 loads each (vs 25 threads x 30-deep chain before)
    if (tid < MAX_IT * SEGS) {
        int pl  = tid / SEGS;
        int sg  = tid % SEGS;
        const int4* p = (const int4*)(partial + (b * MAX_IT + pl) * PSTRIDE)
                        + sg * SEG_I4;
        int s = 0;
#pragma unroll
        for (int c = 0; c < SEG_I4; ++c) {
            int4 v = p[c];
            s += v.x + v.y + v.z + v.w;
        }
        atomicAdd(&scnt[pl], s);
    }
    __syncthreads();
    if (tid == 0) {
        int best = 0, bc = scnt[0];
        for (int it = 1; it < MAX_IT; ++it) {
            int c = scnt[it];
            if (c > bc) { bc = c; best = it; }   // strict > : first-max == np argmax
        }
        int pi = b * MAX_IT + best;
        sw[0] = wsf[pi * 3 + 0];
        sw[1] = wsf[pi * 3 + 1];
        sw[2] = wsf[pi * 3 + 2];
        if (blk == 0) {   // best_w tail: (B,3,1) = 12 floats
            out[(size_t)BN * HW + b * 3 + 0] = sw[0];
            out[(size_t)BN * HW + b * 3 + 1] = sw[1];
            out[(size_t)BN * HW + b * 3 + 2] = sw[2];
        }
    }
    __syncthreads();
    float w0 = sw[0], w1 = sw[1], w2 = sw[2];
    const float4* px = (const float4*)(pts + (size_t)b * 3 * HW);
    const float4* py = px + HW / 4;
    const float4* pz = py + HW / 4;
    int i = blk * 256 + tid;   // element in [0, HW/4)
    float4 x = px[i], y = py[i], z = pz[i];
    float4 r;
    r.x = w0 * x.x + w1 * z.x + w2 - y.x;
    r.y = w0 * x.y + w1 * z.y + w2 - y.y;
    r.z = w0 * x.z + w1 * z.z + w2 - y.z;
    r.w = w0 * x.w + w1 * z.w + w2 - y.w;
    ((float4*)(out + (size_t)b * HW))[i] = r;
}

extern "C" void kernel_launch(void* const* d_in, const int* in_sizes, int n_in,
                              void* d_out, int out_size, void* d_ws, size_t ws_size,
                              hipStream_t stream) {
    const float* pts  = (const float*)d_in[0];
    const int*   rind = (const int*)d_in[1];
    float* out = (float*)d_out;

    float* wsf     = (float*)d_ws;                  // 300 floats
    int*   partial = (int*)(wsf + TOTAL_P * 3 + 4); // 100*128 ints (each slot
                                                    // written before read; no init)

    k_count<<<BN * CHUNKS, 256, 0, stream>>>(pts, rind, wsf, partial);
    k_dist <<<BN * BLOCKS_PER_B, 256, 0, stream>>>(pts, wsf, partial, out);
}